// Round 6
// baseline (487.767 us; speedup 1.0000x reference)
//
#include <hip/hip_runtime.h>

typedef __attribute__((ext_vector_type(4))) float f32x4;
typedef __attribute__((ext_vector_type(8))) __bf16 bf16x8;

#define B_SZ   16
#define T_SZ   256
#define BT_SZ  4096      // B*T
#define N_VOX  20000
#define INDIM  800
#define K1P    1024      // padded K for GEMM1
#define K_DIM  4000
#define KP     4096      // padded K / hidden
#define R_DIM  1000
#define RP     1024      // padded rest

__device__ __forceinline__ unsigned short f2bf(float f) {
  unsigned int u = __builtin_bit_cast(unsigned int, f);
  u += 0x7fffu + ((u >> 16) & 1u);
  return (unsigned short)(u >> 16);
}
__device__ __forceinline__ float bf2f(unsigned short h) {
  unsigned int u = ((unsigned int)h) << 16;
  return __builtin_bit_cast(float, u);
}
__device__ __forceinline__ void gload16(const void* g, void* l) {
  __builtin_amdgcn_global_load_lds(
      (const __attribute__((address_space(1))) void*)g,
      (__attribute__((address_space(3))) void*)l, 16, 0, 0);
}

// ---------- conversion kernels ----------
// x [4096][800] f32 -> xb [4096][1024] bf16, zero-padded
__global__ void cvt_pad_x(const float* __restrict__ src,
                          unsigned short* __restrict__ dst) {
  int i = blockIdx.x * 256 + threadIdx.x;   // slot of 4 ushorts
  int row = i >> 8;                         // 256 slots per 1024-col row
  int c4 = i & 255;
  if (row >= BT_SZ) return;
  ushort4 o = {0, 0, 0, 0};
  if (c4 < INDIM / 4) {
    float4 v = ((const float4*)(src + (size_t)row * INDIM))[c4];
    o.x = f2bf(v.x); o.y = f2bf(v.y); o.z = f2bf(v.z); o.w = f2bf(v.w);
  }
  ((ushort4*)(dst + (size_t)row * K1P))[c4] = o;
}

// W [K,N] f32  ->  WT [Npad, Kpad] bf16 (zero padded)
__global__ void transpose_cvt(const float* __restrict__ W,
                              unsigned short* __restrict__ WT,
                              int K, int N, int Kpad, int Npad) {
  __shared__ float tile[32][33];
  int k0 = blockIdx.x * 32, n0 = blockIdx.y * 32;
  for (int i = threadIdx.y; i < 32; i += 8) {
    int k = k0 + i, n = n0 + threadIdx.x;
    tile[i][threadIdx.x] = (k < K && n < N) ? W[(size_t)k * N + n] : 0.f;
  }
  __syncthreads();
  for (int i = threadIdx.y; i < 32; i += 8) {
    int n = n0 + i, k = k0 + threadIdx.x;
    if (n < Npad && k < Kpad)
      WT[(size_t)n * Kpad + k] = f2bf(tile[threadIdx.x][i]);
  }
}

// ---------- mask / mapping ----------
// border_mask is bool, delivered as int32. 4 columns per thread (int4 loads).
__global__ void covered_kernel(const int* __restrict__ bmask,
                               unsigned char* __restrict__ cov) {
  int n4 = blockIdx.x * 256 + threadIdx.x;
  int b = blockIdx.y;
  if (n4 >= N_VOX / 4) return;
  const int4* p = (const int4*)(bmask + (size_t)b * T_SZ * N_VOX) + n4;
  int4 a = {0, 0, 0, 0};
  for (int t0 = 0; t0 < T_SZ; t0 += 8) {
    int4 c[8];
#pragma unroll
    for (int tt = 0; tt < 8; ++tt)
      c[tt] = p[(size_t)(t0 + tt) * (N_VOX / 4)];
#pragma unroll
    for (int tt = 0; tt < 8; ++tt) {
      a.x |= c[tt].x; a.y |= c[tt].y; a.z |= c[tt].z; a.w |= c[tt].w;
    }
    if (a.x && a.y && a.z && a.w) break;
  }
  uchar4 o;
  o.x = (unsigned char)(a.x != 0); o.y = (unsigned char)(a.y != 0);
  o.z = (unsigned char)(a.z != 0); o.w = (unsigned char)(a.w != 0);
  *(uchar4*)(cov + (size_t)b * N_VOX + (size_t)n4 * 4) = o;
}

// one block (1024 thr) per sample: srcmap[n] = j (index col), K_DIM+rank (rest col), -1 (zero)
__global__ void map_kernel(const int* __restrict__ index,
                           const unsigned char* __restrict__ cov,
                           int* __restrict__ srcmap) {
  int b = blockIdx.x, tid = threadIdx.x;
  int* sm = srcmap + (size_t)b * N_VOX;
  for (int n = tid; n < N_VOX; n += 1024) sm[n] = -1;
  __syncthreads();
  const int* idx = index + (size_t)b * K_DIM;
  for (int j = tid; j < K_DIM; j += 1024) sm[idx[j]] = j;
  __syncthreads();

  __shared__ int wsum[16];
  __shared__ int s_running;
  if (tid == 0) s_running = 0;
  __syncthreads();
  const int lane = tid & 63, wid = tid >> 6;
  const unsigned char* cv = cov + (size_t)b * N_VOX;
  for (int base = 0; base < N_VOX; base += 1024) {
    int n = base + tid;
    bool flag = (n < N_VOX) && (!cv[n]) && (sm[n] < 0);
    unsigned long long bal = __ballot(flag);
    if (lane == 0) wsum[wid] = __popcll(bal);
    __syncthreads();
    int woff = 0, tot = 0;
    for (int w = 0; w < 16; ++w) {
      int c = wsum[w];
      if (w < wid) woff += c;
      tot += c;
    }
    int rank = s_running + woff + __popcll(bal & ((1ull << lane) - 1ull));
    if (flag && rank < R_DIM) sm[n] = K_DIM + rank;
    __syncthreads();
    if (tid == 0) s_running += tot;
    __syncthreads();
  }
}

// ---------- GEMM (m97-style 64 tile) for GEMM3 ----------
template <int BM>
__global__ __launch_bounds__(256) void gemm_bt(
    const unsigned short* __restrict__ A,
    const unsigned short* __restrict__ BTm,
    const float* __restrict__ bias, int nbias,
    unsigned short* __restrict__ C,
    int K, int lda, int ldb, int ldc) {
  constexpr int MI = BM / 32;   // fragment rows per wave
  __shared__ __align__(16) unsigned short As[BM * 32];
  __shared__ __align__(16) unsigned short Bs[128 * 32];
  const int tid = threadIdx.x;
  const int wid = tid >> 6;
  const int lane = tid & 63;
  const int bm = blockIdx.y, bn = blockIdx.x;
  const int wm = wid >> 1, wn = wid & 1;
  const int sub = lane >> 2;    // row within 16-row chunk
  const int quad = lane & 3;    // 16B slot within 64B row

  const int rA0 = wid * 16 + sub;
  const char* gA0 = (const char*)(A + (size_t)(bm * BM + rA0) * lda) + quad * 16;
  const char* gA1 = (const char*)(A + (size_t)(bm * BM + ((BM == 128) ? rA0 + 64 : rA0)) * lda) + quad * 16;
  const char* gB0 = (const char*)(BTm + (size_t)(bn * 128 + rA0) * ldb) + quad * 16;
  const char* gB1 = (const char*)(BTm + (size_t)(bn * 128 + rA0 + 64) * ldb) + quad * 16;

  char* lA0 = (char*)As + wid * 1024 + lane * 16;
  char* lA1 = lA0 + 4096;
  char* lB0 = (char*)Bs + wid * 1024 + lane * 16;
  char* lB1 = lB0 + 4096;

  const int r15 = lane & 15;
  const int kg = lane >> 4;

  f32x4 acc[MI][4] = {};

  for (int kt = 0; kt < K; kt += 32) {
    const int kb = kt * 2;
    gload16(gA0 + kb, lA0);
    if constexpr (BM == 128) gload16(gA1 + kb, lA1);
    gload16(gB0 + kb, lB0);
    gload16(gB1 + kb, lB1);
    __syncthreads();
    bf16x8 af[MI], bfr[4];
#pragma unroll
    for (int i = 0; i < MI; ++i)
      af[i] = *(const bf16x8*)&As[(wm * (BM / 2) + i * 16 + r15) * 32 + kg * 8];
#pragma unroll
    for (int j = 0; j < 4; ++j)
      bfr[j] = *(const bf16x8*)&Bs[(wn * 64 + j * 16 + r15) * 32 + kg * 8];
#pragma unroll
    for (int i = 0; i < MI; ++i)
#pragma unroll
      for (int j = 0; j < 4; ++j)
        acc[i][j] = __builtin_amdgcn_mfma_f32_16x16x32_bf16(af[i], bfr[j], acc[i][j], 0, 0, 0);
    __syncthreads();
  }

#pragma unroll
  for (int i = 0; i < MI; ++i) {
    const int row0 = bm * BM + wm * (BM / 2) + i * 16 + kg * 4;
#pragma unroll
    for (int j = 0; j < 4; ++j) {
      const int col = bn * 128 + wn * 64 + j * 16 + r15;
      const float bv = bias[(col < nbias) ? col : (nbias - 1)];
#pragma unroll
      for (int r = 0; r < 4; ++r)
        C[(size_t)(row0 + r) * ldc + col] = f2bf(acc[i][j][r] + bv);
    }
  }
}

// ---------- GEMM 256x256 8-phase (T3+T4+T5), K-split-half LDS ----------
// 512 threads = 8 waves (2m x 4n); wave tile 128x64; BK=64 (2 k-halves of 32).
// LDS 128 KiB: buf[2] x { A[2 kh][256][32], B[2 kh][256][32] } bf16, 64B rows.
// 64B rows give the even 8-lanes-per-bank-group spread (b128 floor) with
// linear addressing, so global_load_lds-direct staging stays legal (no swizzle).
// NOTE (r6): no explicit lgkmcnt(0)/sched_barrier before MFMA — ds_reads are
// compiler-visible, so hipcc emits fine-grained lgkmcnt(N) waits and can
// overlap read-latency with MFMA issue (m141: hard pinning costs ~40%).
__global__ __launch_bounds__(512, 2) void gemm256(
    const unsigned short* __restrict__ A,
    const unsigned short* __restrict__ BTm,
    const float* __restrict__ bias, int nbias,
    unsigned short* __restrict__ C,
    int K, int lda, int ldb, int ldc) {
  __shared__ __align__(16) char smem[131072];
  const int tid = threadIdx.x;
  const int wid = tid >> 6, lane = tid & 63;
  const int wm = wid >> 2, wn = wid & 3;
  const int r15 = lane & 15, kg = lane >> 4;
  const int bm = blockIdx.y, bn = blockIdx.x;

  // staging: thread covers 16B at LDS offset L*8192 + tid*16 of a 16KB half
  const int srow = tid >> 2;            // 0..127
  const int scol = (tid & 3) * 8;       // ushort offset within 64B row
  const unsigned short* gA = A + (size_t)(bm * 256 + srow) * lda + scol;
  const unsigned short* gB = BTm + (size_t)(bn * 256 + srow) * ldb + scol;

  // ds_read base byte offsets (within a 16KB half)
  const int aoff = (wm * 128 + r15) * 64 + kg * 16;   // + mh*4096 + i*1024
  const int boff = (wn * 64 + r15) * 64 + kg * 16;    // + j*1024

  f32x4 acc[8][4] = {};
  bf16x8 bfr[4];

#define STAGE_HALF(S, MAT, KH, TN)                                            \
  {                                                                           \
    const unsigned short* g =                                                 \
        ((MAT) ? gB : gA) + (size_t)(TN) * 64 + (KH) * 32;                    \
    char* l = smem + (S) * 65536 + (MAT) * 32768 + (KH) * 16384 + tid * 16;   \
    gload16(g, l);                                                            \
    gload16(g + (size_t)128 * ((MAT) ? ldb : lda), l + 8192);                 \
  }

#define PHASE(S, KS, MH, TN, DOVM)                                            \
  {                                                                           \
    bf16x8 af[4];                                                             \
    if ((MH) == 0) {                                                          \
      _Pragma("unroll")                                                       \
      for (int j = 0; j < 4; ++j)                                             \
        bfr[j] = *(const bf16x8*)(smem + (S) * 65536 + 32768 +                \
                                  (KS) * 16384 + boff + j * 1024);            \
    }                                                                         \
    _Pragma("unroll")                                                         \
    for (int i = 0; i < 4; ++i)                                               \
      af[i] = *(const bf16x8*)(smem + (S) * 65536 + (KS) * 16384 +            \
                               (MH) * 4096 + aoff + i * 1024);                \
    STAGE_HALF((S) ^ 1, (MH), (KS), TN)                                       \
    if (DOVM) asm volatile("s_waitcnt vmcnt(4)" ::: "memory");                \
    asm volatile("s_barrier" ::: "memory");                                   \
    __builtin_amdgcn_s_setprio(1);                                            \
    _Pragma("unroll")                                                         \
    for (int i = 0; i < 4; ++i)                                               \
      _Pragma("unroll")                                                       \
      for (int j = 0; j < 4; ++j)                                             \
        acc[(MH) * 4 + i][j] = __builtin_amdgcn_mfma_f32_16x16x32_bf16(       \
            af[i], bfr[j], acc[(MH) * 4 + i][j], 0, 0, 0);                    \
    __builtin_amdgcn_s_setprio(0);                                            \
    asm volatile("s_barrier" ::: "memory");                                   \
  }

#define TILE4(S, TN)                                                          \
  PHASE(S, 0, 0, TN, 0)                                                       \
  PHASE(S, 0, 1, TN, 1)                                                       \
  PHASE(S, 1, 0, TN, 0)                                                       \
  PHASE(S, 1, 1, TN, 1)

  const int NT = K >> 6;   // K/64, must be even
  // prologue: stage tile 0 fully into buf0
  STAGE_HALF(0, 0, 0, 0)
  STAGE_HALF(0, 1, 0, 0)
  STAGE_HALF(0, 0, 1, 0)
  STAGE_HALF(0, 1, 1, 0)
  asm volatile("s_waitcnt vmcnt(4)" ::: "memory");
  asm volatile("s_barrier" ::: "memory");

  for (int tp = 0; tp < NT; tp += 2) {
    const int tn1 = tp + 1;                          // always < NT (NT even)
    TILE4(0, tn1)
    const int tn2 = (tp + 2 < NT) ? tp + 2 : NT - 1; // clamp: harmless restage
    TILE4(1, tn2)
  }

#undef STAGE_HALF
#undef PHASE
#undef TILE4

  // epilogue
#pragma unroll
  for (int f = 0; f < 8; ++f) {
    const int row0 = bm * 256 + wm * 128 + f * 16 + kg * 4;
#pragma unroll
    for (int j = 0; j < 4; ++j) {
      const int col = bn * 256 + wn * 64 + j * 16 + r15;
      const float bv = bias[(col < nbias) ? col : (nbias - 1)];
#pragma unroll
      for (int r = 0; r < 4; ++r)
        C[(size_t)(row0 + r) * ldc + col] = f2bf(acc[f][j][r] + bv);
    }
  }
}

// ---------- final output assembly (x4 vectorized; N_VOX % 4 == 0) ----------
__global__ void fill_out(const int* __restrict__ srcmap,
                         const unsigned short* __restrict__ h2b,
                         const unsigned short* __restrict__ xrb,
                         float* __restrict__ out) {
  int n4 = blockIdx.x * 256 + threadIdx.x;
  if (n4 >= N_VOX / 4) return;
  int t = blockIdx.y, b = blockIdx.z;
  size_t bt = (size_t)b * T_SZ + t;
  const int4 sm = ((const int4*)(srcmap + (size_t)b * N_VOX))[n4];
  const unsigned short* hrow = h2b + bt * KP;
  const unsigned short* xrow = xrb + bt * RP;
  float4 v;
  v.x = (sm.x < 0) ? 0.f : bf2f(sm.x < K_DIM ? hrow[sm.x] : xrow[sm.x - K_DIM]);
  v.y = (sm.y < 0) ? 0.f : bf2f(sm.y < K_DIM ? hrow[sm.y] : xrow[sm.y - K_DIM]);
  v.z = (sm.z < 0) ? 0.f : bf2f(sm.z < K_DIM ? hrow[sm.z] : xrow[sm.z - K_DIM]);
  v.w = (sm.w < 0) ? 0.f : bf2f(sm.w < K_DIM ? hrow[sm.w] : xrow[sm.w - K_DIM]);
  ((float4*)(out + bt * N_VOX))[n4] = v;
}

extern "C" void kernel_launch(void* const* d_in, const int* in_sizes, int n_in,
                              void* d_out, int out_size, void* d_ws, size_t ws_size,
                              hipStream_t stream) {
  const float* x          = (const float*)d_in[0];
  const int* bm           = (const int*)d_in[1];   // bool -> int32 per harness contract
  const int* index        = (const int*)d_in[2];
  const float* W1         = (const float*)d_in[3];
  const float* b1         = (const float*)d_in[4];
  const float* W2         = (const float*)d_in[5];
  const float* b2         = (const float*)d_in[6];
  const float* W3         = (const float*)d_in[7];
  const float* b3         = (const float*)d_in[8];
  float* out = (float*)d_out;

  char* ws = (char*)d_ws;
  size_t off = 0;
  auto alloc = [&](size_t bytes) -> void* {
    void* p = ws + off;
    off += (bytes + 255) & ~(size_t)255;
    return p;
  };
  unsigned short* xb  = (unsigned short*)alloc((size_t)BT_SZ * K1P * 2);
  unsigned short* w1t = (unsigned short*)alloc((size_t)KP * K1P * 2);
  unsigned short* w2t = (unsigned short*)alloc((size_t)KP * KP * 2);
  unsigned short* w3t = (unsigned short*)alloc((size_t)RP * KP * 2);
  unsigned short* h1b = (unsigned short*)alloc((size_t)BT_SZ * KP * 2);
  unsigned short* h2b = (unsigned short*)alloc((size_t)BT_SZ * KP * 2);
  unsigned short* xrb = (unsigned short*)alloc((size_t)BT_SZ * RP * 2);
  unsigned char* cov = (unsigned char*)alloc((size_t)B_SZ * N_VOX);
  int* srcmap = (int*)alloc((size_t)B_SZ * N_VOX * 4);

  // conversions
  cvt_pad_x<<<BT_SZ * (K1P / 4) / 256, 256, 0, stream>>>(x, xb);
  {
    dim3 g(K1P / 32, KP / 32);     // W1: [800,4000] -> [4096,1024]
    transpose_cvt<<<g, dim3(32, 8), 0, stream>>>(W1, w1t, INDIM, K_DIM, K1P, KP);
  }
  {
    dim3 g(KP / 32, KP / 32);      // W2: [4000,4000] -> [4096,4096]
    transpose_cvt<<<g, dim3(32, 8), 0, stream>>>(W2, w2t, K_DIM, K_DIM, KP, KP);
  }
  {
    dim3 g(KP / 32, RP / 32);      // W3: [4000,1000] -> [1024,4096]
    transpose_cvt<<<g, dim3(32, 8), 0, stream>>>(W3, w3t, K_DIM, R_DIM, KP, RP);
  }

  // coverage + mapping
  {
    dim3 g((N_VOX / 4 + 255) / 256, B_SZ);
    covered_kernel<<<g, 256, 0, stream>>>(bm, cov);
  }
  map_kernel<<<B_SZ, 1024, 0, stream>>>(index, cov, srcmap);

  // GEMM chain
  {
    dim3 g(KP / 256, BT_SZ / 256);   // GEMM1 on 8-phase, K padded to 1024
    gemm256<<<g, 512, 0, stream>>>(xb, w1t, b1, K_DIM, h1b, K1P, K1P, K1P, KP);
  }
  {
    dim3 g(KP / 256, BT_SZ / 256);   // GEMM2
    gemm256<<<g, 512, 0, stream>>>(h1b, w2t, b2, K_DIM, h2b, KP, KP, KP, KP);
  }
  {
    dim3 g(RP / 128, BT_SZ / 64);    // GEMM3: BM=64 -> 512 blocks = 2/CU
    gemm_bt<64><<<g, 256, 0, stream>>>(h2b, w3t, b3, R_DIM, xrb, KP, KP, KP, RP);
  }

  // output assembly
  {
    dim3 g((N_VOX / 4 + 255) / 256, T_SZ, B_SZ);
    fill_out<<<g, 256, 0, stream>>>(srcmap, h2b, xrb, out);
  }
}

// Round 7
// 433.128 us; speedup vs baseline: 1.1261x; 1.1261x over previous
//
#include <hip/hip_runtime.h>

typedef __attribute__((ext_vector_type(4))) float f32x4;
typedef __attribute__((ext_vector_type(8))) __bf16 bf16x8;

#define B_SZ   16
#define T_SZ   256
#define BT_SZ  4096      // B*T
#define N_VOX  20000
#define INDIM  800
#define K1P    896       // padded K for GEMM1 (NT=14, even)
#define K_DIM  4000
#define KP     4096      // padded K / hidden
#define R_DIM  1000
#define RP     1024      // padded rest
#define SPLITK 4

__device__ __forceinline__ unsigned short f2bf(float f) {
  unsigned int u = __builtin_bit_cast(unsigned int, f);
  u += 0x7fffu + ((u >> 16) & 1u);
  return (unsigned short)(u >> 16);
}
__device__ __forceinline__ float bf2f(unsigned short h) {
  unsigned int u = ((unsigned int)h) << 16;
  return __builtin_bit_cast(float, u);
}
__device__ __forceinline__ void gload16(const void* g, void* l) {
  __builtin_amdgcn_global_load_lds(
      (const __attribute__((address_space(1))) void*)g,
      (__attribute__((address_space(3))) void*)l, 16, 0, 0);
}

// ---------- conversion kernels ----------
// x [4096][800] f32 -> xb [4096][896] bf16, zero-padded. One block per row.
__global__ void cvt_pad_x(const float* __restrict__ src,
                          unsigned short* __restrict__ dst) {
  int row = blockIdx.x;
  int c4 = threadIdx.x;
  if (c4 >= K1P / 4) return;
  ushort4 o = {0, 0, 0, 0};
  if (c4 < INDIM / 4) {
    float4 v = ((const float4*)(src + (size_t)row * INDIM))[c4];
    o.x = f2bf(v.x); o.y = f2bf(v.y); o.z = f2bf(v.z); o.w = f2bf(v.w);
  }
  ((ushort4*)(dst + (size_t)row * K1P))[c4] = o;
}

// W [K,N] f32  ->  WT [Npad, Kpad] bf16 (zero padded)
__global__ void transpose_cvt(const float* __restrict__ W,
                              unsigned short* __restrict__ WT,
                              int K, int N, int Kpad, int Npad) {
  __shared__ float tile[32][33];
  int k0 = blockIdx.x * 32, n0 = blockIdx.y * 32;
  for (int i = threadIdx.y; i < 32; i += 8) {
    int k = k0 + i, n = n0 + threadIdx.x;
    tile[i][threadIdx.x] = (k < K && n < N) ? W[(size_t)k * N + n] : 0.f;
  }
  __syncthreads();
  for (int i = threadIdx.y; i < 32; i += 8) {
    int n = n0 + i, k = k0 + threadIdx.x;
    if (n < Npad && k < Kpad)
      WT[(size_t)n * Kpad + k] = f2bf(tile[threadIdx.x][i]);
  }
}

// ---------- mask / mapping ----------
// border_mask is bool, delivered as int32. 4 columns per thread (int4 loads).
__global__ void covered_kernel(const int* __restrict__ bmask,
                               unsigned char* __restrict__ cov) {
  int n4 = blockIdx.x * 256 + threadIdx.x;
  int b = blockIdx.y;
  if (n4 >= N_VOX / 4) return;
  const int4* p = (const int4*)(bmask + (size_t)b * T_SZ * N_VOX) + n4;
  int4 a = {0, 0, 0, 0};
  for (int t0 = 0; t0 < T_SZ; t0 += 8) {
    int4 c[8];
#pragma unroll
    for (int tt = 0; tt < 8; ++tt)
      c[tt] = p[(size_t)(t0 + tt) * (N_VOX / 4)];
#pragma unroll
    for (int tt = 0; tt < 8; ++tt) {
      a.x |= c[tt].x; a.y |= c[tt].y; a.z |= c[tt].z; a.w |= c[tt].w;
    }
    if (a.x && a.y && a.z && a.w) break;
  }
  uchar4 o;
  o.x = (unsigned char)(a.x != 0); o.y = (unsigned char)(a.y != 0);
  o.z = (unsigned char)(a.z != 0); o.w = (unsigned char)(a.w != 0);
  *(uchar4*)(cov + (size_t)b * N_VOX + (size_t)n4 * 4) = o;
}

// one block (1024 thr) per sample: srcmap[n] = j (index col), K_DIM+rank (rest col), -1 (zero)
__global__ void map_kernel(const int* __restrict__ index,
                           const unsigned char* __restrict__ cov,
                           int* __restrict__ srcmap) {
  int b = blockIdx.x, tid = threadIdx.x;
  int* sm = srcmap + (size_t)b * N_VOX;
  for (int n = tid; n < N_VOX; n += 1024) sm[n] = -1;
  __syncthreads();
  const int* idx = index + (size_t)b * K_DIM;
  for (int j = tid; j < K_DIM; j += 1024) sm[idx[j]] = j;
  __syncthreads();

  __shared__ int wsum[16];
  __shared__ int s_running;
  if (tid == 0) s_running = 0;
  __syncthreads();
  const int lane = tid & 63, wid = tid >> 6;
  const unsigned char* cv = cov + (size_t)b * N_VOX;
  for (int base = 0; base < N_VOX; base += 1024) {
    int n = base + tid;
    bool flag = (n < N_VOX) && (!cv[n]) && (sm[n] < 0);
    unsigned long long bal = __ballot(flag);
    if (lane == 0) wsum[wid] = __popcll(bal);
    __syncthreads();
    int woff = 0, tot = 0;
    for (int w = 0; w < 16; ++w) {
      int c = wsum[w];
      if (w < wid) woff += c;
      tot += c;
    }
    int rank = s_running + woff + __popcll(bal & ((1ull << lane) - 1ull));
    if (flag && rank < R_DIM) sm[n] = K_DIM + rank;
    __syncthreads();
    if (tid == 0) s_running += tot;
    __syncthreads();
  }
}

// ---------- GEMM (m97-style 128 tile), optional split-K over blockIdx.z ----------
// SPLIT: A/B column-offset by z*K, raw partial (no bias) to C + z*zstride.
template <int BM, bool SPLIT>
__global__ __launch_bounds__(256) void gemm_bt(
    const unsigned short* __restrict__ A,
    const unsigned short* __restrict__ BTm,
    const float* __restrict__ bias, int nbias,
    unsigned short* __restrict__ C,
    int K, int lda, int ldb, int ldc, size_t zstride) {
  constexpr int MI = BM / 32;   // fragment rows per wave
  __shared__ __align__(16) unsigned short As[BM * 32];
  __shared__ __align__(16) unsigned short Bs[128 * 32];
  const int tid = threadIdx.x;
  const int wid = tid >> 6;
  const int lane = tid & 63;
  const int bm = blockIdx.y, bn = blockIdx.x;
  if (SPLIT) {
    int kz = blockIdx.z;
    A += (size_t)kz * K;
    BTm += (size_t)kz * K;
    C += (size_t)kz * zstride;
  }
  const int wm = wid >> 1, wn = wid & 1;
  const int sub = lane >> 2;    // row within 16-row chunk
  const int quad = lane & 3;    // 16B slot within 64B row

  const int rA0 = wid * 16 + sub;
  const char* gA0 = (const char*)(A + (size_t)(bm * BM + rA0) * lda) + quad * 16;
  const char* gA1 = (const char*)(A + (size_t)(bm * BM + ((BM == 128) ? rA0 + 64 : rA0)) * lda) + quad * 16;
  const char* gB0 = (const char*)(BTm + (size_t)(bn * 128 + rA0) * ldb) + quad * 16;
  const char* gB1 = (const char*)(BTm + (size_t)(bn * 128 + rA0 + 64) * ldb) + quad * 16;

  char* lA0 = (char*)As + wid * 1024 + lane * 16;
  char* lA1 = lA0 + 4096;
  char* lB0 = (char*)Bs + wid * 1024 + lane * 16;
  char* lB1 = lB0 + 4096;

  const int r15 = lane & 15;
  const int kg = lane >> 4;

  f32x4 acc[MI][4] = {};

  for (int kt = 0; kt < K; kt += 32) {
    const int kb = kt * 2;
    gload16(gA0 + kb, lA0);
    if constexpr (BM == 128) gload16(gA1 + kb, lA1);
    gload16(gB0 + kb, lB0);
    gload16(gB1 + kb, lB1);
    __syncthreads();
    bf16x8 af[MI], bfr[4];
#pragma unroll
    for (int i = 0; i < MI; ++i)
      af[i] = *(const bf16x8*)&As[(wm * (BM / 2) + i * 16 + r15) * 32 + kg * 8];
#pragma unroll
    for (int j = 0; j < 4; ++j)
      bfr[j] = *(const bf16x8*)&Bs[(wn * 64 + j * 16 + r15) * 32 + kg * 8];
#pragma unroll
    for (int i = 0; i < MI; ++i)
#pragma unroll
      for (int j = 0; j < 4; ++j)
        acc[i][j] = __builtin_amdgcn_mfma_f32_16x16x32_bf16(af[i], bfr[j], acc[i][j], 0, 0, 0);
    __syncthreads();
  }

#pragma unroll
  for (int i = 0; i < MI; ++i) {
    const int row0 = bm * BM + wm * (BM / 2) + i * 16 + kg * 4;
#pragma unroll
    for (int j = 0; j < 4; ++j) {
      const int col = bn * 128 + wn * 64 + j * 16 + r15;
      float bv = 0.f;
      if constexpr (!SPLIT) bv = bias[(col < nbias) ? col : (nbias - 1)];
#pragma unroll
      for (int r = 0; r < 4; ++r)
        C[(size_t)(row0 + r) * ldc + col] = f2bf(acc[i][j][r] + bv);
    }
  }
}

// reduce split-K partials + bias -> xrb bf16. one ushort4 slot per thread.
__global__ void reduce_splitk(const unsigned short* __restrict__ part,
                              const float* __restrict__ bias,
                              unsigned short* __restrict__ out) {
  int i = blockIdx.x * 256 + threadIdx.x;      // over BT_SZ*RP/4 slots
  if (i >= BT_SZ * RP / 4) return;
  const size_t zs = (size_t)BT_SZ * RP / 4;    // in ushort4 units
  float s[4] = {0.f, 0.f, 0.f, 0.f};
#pragma unroll
  for (int z = 0; z < SPLITK; ++z) {
    ushort4 p = ((const ushort4*)part)[z * zs + i];
    s[0] += bf2f(p.x); s[1] += bf2f(p.y); s[2] += bf2f(p.z); s[3] += bf2f(p.w);
  }
  int col = (i * 4) & (RP - 1);
  ushort4 o;
  o.x = f2bf(s[0] + bias[(col     < R_DIM) ? col     : R_DIM - 1]);
  o.y = f2bf(s[1] + bias[(col + 1 < R_DIM) ? col + 1 : R_DIM - 1]);
  o.z = f2bf(s[2] + bias[(col + 2 < R_DIM) ? col + 2 : R_DIM - 1]);
  o.w = f2bf(s[3] + bias[(col + 3 < R_DIM) ? col + 3 : R_DIM - 1]);
  ((ushort4*)out)[i] = o;
}

// ---------- GEMM 256x256 8-phase (T2+T3+T4+T5), K-split-half LDS ----------
// 512 threads = 8 waves (2m x 4n); wave tile 128x64; BK=64 (2 k-halves of 32).
// LDS 128 KiB: buf[2] x { A[2 kh][256][32], B[2 kh][256][32] } bf16, 64B rows.
// T2 swizzle (rule #21 both-sides): LDS dest stays LINEAR for global_load_lds;
// the per-lane GLOBAL source column is pre-permuted by the involution
// col_bytes ^= 32*((row>>3)&1), and every ds_read applies the same XOR.
// This breaks the 8-way bank conflict (64B-row stride, 16 lanes on one
// bank-quad pair) down to 4-way (m201-residual level). Data and MFMA
// accumulation order are bit-identical to the unswizzled kernel.
__global__ __launch_bounds__(512, 2) void gemm256(
    const unsigned short* __restrict__ A,
    const unsigned short* __restrict__ BTm,
    const float* __restrict__ bias, int nbias,
    unsigned short* __restrict__ C,
    int K, int lda, int ldb, int ldc) {
  __shared__ __align__(16) char smem[131072];
  const int tid = threadIdx.x;
  const int wid = tid >> 6, lane = tid & 63;
  const int wm = wid >> 2, wn = wid & 3;
  const int r15 = lane & 15, kg = lane >> 4;
  const int bm = blockIdx.y, bn = blockIdx.x;

  // staging: thread covers 16B at LDS offset L*8192 + tid*16 of a 16KB half
  const int srow = tid >> 2;                       // 0..127 (row within layer)
  const int scol = ((tid & 3) * 8) ^ ((srow & 8) ? 16 : 0);  // pre-swizzled src col (ushorts)
  const unsigned short* gA = A + (size_t)(bm * 256 + srow) * lda + scol;
  const unsigned short* gB = BTm + (size_t)(bn * 256 + srow) * ldb + scol;

  // ds_read base byte offsets (within a 16KB half), read-side XOR
  const int cxor = (kg * 16) ^ ((r15 & 8) ? 32 : 0);
  const int aoff = (wm * 128 + r15) * 64 + cxor;   // + mh*4096 + i*1024
  const int boff = (wn * 64 + r15) * 64 + cxor;    // + j*1024

  f32x4 acc[8][4] = {};
  bf16x8 bfr[4];

#define STAGE_HALF(S, MAT, KH, TN)                                            \
  {                                                                           \
    const unsigned short* g =                                                 \
        ((MAT) ? gB : gA) + (size_t)(TN) * 64 + (KH) * 32;                    \
    char* l = smem + (S) * 65536 + (MAT) * 32768 + (KH) * 16384 + tid * 16;   \
    gload16(g, l);                                                            \
    gload16(g + (size_t)128 * ((MAT) ? ldb : lda), l + 8192);                 \
  }

#define PHASE(S, KS, MH, TN, DOVM)                                            \
  {                                                                           \
    bf16x8 af[4];                                                             \
    if ((MH) == 0) {                                                          \
      _Pragma("unroll")                                                       \
      for (int j = 0; j < 4; ++j)                                             \
        bfr[j] = *(const bf16x8*)(smem + (S) * 65536 + 32768 +                \
                                  (KS) * 16384 + boff + j * 1024);            \
    }                                                                         \
    _Pragma("unroll")                                                         \
    for (int i = 0; i < 4; ++i)                                               \
      af[i] = *(const bf16x8*)(smem + (S) * 65536 + (KS) * 16384 +            \
                               (MH) * 4096 + aoff + i * 1024);                \
    STAGE_HALF((S) ^ 1, (MH), (KS), TN)                                       \
    if (DOVM) asm volatile("s_waitcnt vmcnt(4)" ::: "memory");                \
    asm volatile("s_barrier" ::: "memory");                                   \
    __builtin_amdgcn_s_setprio(1);                                            \
    _Pragma("unroll")                                                         \
    for (int i = 0; i < 4; ++i)                                               \
      _Pragma("unroll")                                                       \
      for (int j = 0; j < 4; ++j)                                             \
        acc[(MH) * 4 + i][j] = __builtin_amdgcn_mfma_f32_16x16x32_bf16(       \
            af[i], bfr[j], acc[(MH) * 4 + i][j], 0, 0, 0);                    \
    __builtin_amdgcn_s_setprio(0);                                            \
    asm volatile("s_barrier" ::: "memory");                                   \
  }

#define TILE4(S, TN)                                                          \
  PHASE(S, 0, 0, TN, 0)                                                       \
  PHASE(S, 0, 1, TN, 1)                                                       \
  PHASE(S, 1, 0, TN, 0)                                                       \
  PHASE(S, 1, 1, TN, 1)

  const int NT = K >> 6;   // K/64, must be even
  // prologue: stage tile 0 fully into buf0
  STAGE_HALF(0, 0, 0, 0)
  STAGE_HALF(0, 1, 0, 0)
  STAGE_HALF(0, 0, 1, 0)
  STAGE_HALF(0, 1, 1, 0)
  asm volatile("s_waitcnt vmcnt(4)" ::: "memory");
  asm volatile("s_barrier" ::: "memory");

  for (int tp = 0; tp < NT; tp += 2) {
    const int tn1 = tp + 1;                          // always < NT (NT even)
    TILE4(0, tn1)
    const int tn2 = (tp + 2 < NT) ? tp + 2 : NT - 1; // clamp: harmless restage
    TILE4(1, tn2)
  }

#undef STAGE_HALF
#undef PHASE
#undef TILE4

  // epilogue
#pragma unroll
  for (int f = 0; f < 8; ++f) {
    const int row0 = bm * 256 + wm * 128 + f * 16 + kg * 4;
#pragma unroll
    for (int j = 0; j < 4; ++j) {
      const int col = bn * 256 + wn * 64 + j * 16 + r15;
      const float bv = bias[(col < nbias) ? col : (nbias - 1)];
#pragma unroll
      for (int r = 0; r < 4; ++r)
        C[(size_t)(row0 + r) * ldc + col] = f2bf(acc[f][j][r] + bv);
    }
  }
}

// ---------- final output assembly (x4 vectorized; N_VOX % 4 == 0) ----------
// nontemporal stores: out (327MB) is never re-read -> don't thrash L2/L3.
__global__ void fill_out(const int* __restrict__ srcmap,
                         const unsigned short* __restrict__ h2b,
                         const unsigned short* __restrict__ xrb,
                         float* __restrict__ out) {
  int n4 = blockIdx.x * 256 + threadIdx.x;
  if (n4 >= N_VOX / 4) return;
  int t = blockIdx.y, b = blockIdx.z;
  size_t bt = (size_t)b * T_SZ + t;
  const int4 sm = ((const int4*)(srcmap + (size_t)b * N_VOX))[n4];
  const unsigned short* hrow = h2b + bt * KP;
  const unsigned short* xrow = xrb + bt * RP;
  f32x4 v;
  v.x = (sm.x < 0) ? 0.f : bf2f(sm.x < K_DIM ? hrow[sm.x] : xrow[sm.x - K_DIM]);
  v.y = (sm.y < 0) ? 0.f : bf2f(sm.y < K_DIM ? hrow[sm.y] : xrow[sm.y - K_DIM]);
  v.z = (sm.z < 0) ? 0.f : bf2f(sm.z < K_DIM ? hrow[sm.z] : xrow[sm.z - K_DIM]);
  v.w = (sm.w < 0) ? 0.f : bf2f(sm.w < K_DIM ? hrow[sm.w] : xrow[sm.w - K_DIM]);
  __builtin_nontemporal_store(v, (f32x4*)(out + bt * N_VOX) + n4);
}

extern "C" void kernel_launch(void* const* d_in, const int* in_sizes, int n_in,
                              void* d_out, int out_size, void* d_ws, size_t ws_size,
                              hipStream_t stream) {
  const float* x          = (const float*)d_in[0];
  const int* bm           = (const int*)d_in[1];   // bool -> int32 per harness contract
  const int* index        = (const int*)d_in[2];
  const float* W1         = (const float*)d_in[3];
  const float* b1         = (const float*)d_in[4];
  const float* W2         = (const float*)d_in[5];
  const float* b2         = (const float*)d_in[6];
  const float* W3         = (const float*)d_in[7];
  const float* b3         = (const float*)d_in[8];
  float* out = (float*)d_out;

  char* ws = (char*)d_ws;
  size_t off = 0;
  auto alloc = [&](size_t bytes) -> void* {
    void* p = ws + off;
    off += (bytes + 255) & ~(size_t)255;
    return p;
  };
  unsigned short* xb   = (unsigned short*)alloc((size_t)BT_SZ * K1P * 2);
  unsigned short* w1t  = (unsigned short*)alloc((size_t)KP * K1P * 2);
  unsigned short* w2t  = (unsigned short*)alloc((size_t)KP * KP * 2);
  unsigned short* w3t  = (unsigned short*)alloc((size_t)RP * KP * 2);
  unsigned short* h1b  = (unsigned short*)alloc((size_t)BT_SZ * KP * 2);
  unsigned short* h2b  = (unsigned short*)alloc((size_t)BT_SZ * KP * 2);
  unsigned short* xrb  = (unsigned short*)alloc((size_t)BT_SZ * RP * 2);
  unsigned short* xpart = (unsigned short*)alloc((size_t)SPLITK * BT_SZ * RP * 2);
  unsigned char* cov = (unsigned char*)alloc((size_t)B_SZ * N_VOX);
  int* srcmap = (int*)alloc((size_t)B_SZ * N_VOX * 4);

  // conversions
  cvt_pad_x<<<BT_SZ, 256, 0, stream>>>(x, xb);
  {
    dim3 g(K1P / 32, KP / 32);     // W1: [800,4000] -> [4096,896]
    transpose_cvt<<<g, dim3(32, 8), 0, stream>>>(W1, w1t, INDIM, K_DIM, K1P, KP);
  }
  {
    dim3 g(KP / 32, KP / 32);      // W2: [4000,4000] -> [4096,4096]
    transpose_cvt<<<g, dim3(32, 8), 0, stream>>>(W2, w2t, K_DIM, K_DIM, KP, KP);
  }
  {
    dim3 g(KP / 32, RP / 32);      // W3: [4000,1000] -> [1024,4096]
    transpose_cvt<<<g, dim3(32, 8), 0, stream>>>(W3, w3t, K_DIM, R_DIM, KP, RP);
  }

  // coverage + mapping
  {
    dim3 g((N_VOX / 4 + 255) / 256, B_SZ);
    covered_kernel<<<g, 256, 0, stream>>>(bm, cov);
  }
  map_kernel<<<B_SZ, 1024, 0, stream>>>(index, cov, srcmap);

  // GEMM chain
  {
    dim3 g(KP / 256, BT_SZ / 256);   // GEMM1 on 8-phase, K padded to 896
    gemm256<<<g, 512, 0, stream>>>(xb, w1t, b1, K_DIM, h1b, K1P, K1P, K1P, KP);
  }
  {
    dim3 g(KP / 256, BT_SZ / 256);   // GEMM2
    gemm256<<<g, 512, 0, stream>>>(h1b, w2t, b2, K_DIM, h2b, KP, KP, KP, KP);
  }
  {
    dim3 g(RP / 128, BT_SZ / 128, SPLITK);  // GEMM3: split-K=4, 1024 blocks
    gemm_bt<128, true><<<g, 256, 0, stream>>>(h2b, w3t, nullptr, 0, xpart,
                                              KP / SPLITK, KP, KP, RP,
                                              (size_t)BT_SZ * RP);
  }
  reduce_splitk<<<(BT_SZ * RP / 4 + 255) / 256, 256, 0, stream>>>(xpart, b3, xrb);

  // output assembly
  {
    dim3 g((N_VOX / 4 + 255) / 256, T_SZ, B_SZ);
    fill_out<<<g, 256, 0, stream>>>(srcmap, h2b, xrb, out);
  }
}